// Round 6
// baseline (906.455 us; speedup 1.0000x reference)
//
#include <hip/hip_runtime.h>
#include <hip/hip_bf16.h>
#include <math.h>

typedef __bf16 bf16_t;
typedef __bf16 bf16x8 __attribute__((ext_vector_type(8)));
typedef float f32x4 __attribute__((ext_vector_type(4)));

// async 16B global->LDS (LDS dest must be wave-uniform base + lane*16)
__device__ __forceinline__ void gload16(const bf16_t* g, bf16_t* l) {
  __builtin_amdgcn_global_load_lds(
      (const __attribute__((address_space(1))) unsigned int*)g,
      (__attribute__((address_space(3))) unsigned int*)l, 16, 0, 0);
}

// LDS tiles are [rows][64] bf16 (128 B row stride), contents XOR-swizzled:
// LDS[row][chunk j] holds G[row][chunk j ^ (row&7)]  (chunk = 8 bf16 = 16 B).

// ---------------------------------------------------------------------------
// Layer GEMM: out[M,N] = A[M,K] @ W[N,K]^T (+bias, +epilogue)
// EPI 0: bf16 out = acc + bias            (QKV)
// EPI 1: bf16 out = gelu(acc + bias)      (FFN1)
// EPI 4: f32 atomicAdd(out, acc [+bias])  (proj / FFN2 split-K residual)
// Tile 128(M)x64(N), BK=64, 128 threads = 2 waves, each wave 64x64.
// ---------------------------------------------------------------------------
template<int EPI>
__global__ __launch_bounds__(128, 3) void gemm_bt(
    const bf16_t* __restrict__ A, const bf16_t* __restrict__ W,
    const float* __restrict__ bias,
    bf16_t* __restrict__ obf, float* __restrict__ of32,
    int M, int N, int K, int kLen)
{
  __shared__ bf16_t As[128 * 64];
  __shared__ bf16_t Bs[64 * 64];
  const int tid  = threadIdx.x;
  const int lane = tid & 63;
  const int w    = tid >> 6;          // 0..1, wave's 64-row band
  const long m0 = (long)blockIdx.y * 128;
  const long n0 = (long)blockIdx.x * 64;
  const int k0 = blockIdx.z * kLen;
  const int k1 = k0 + kLen;

  f32x4 acc[4][4] = {};

  const int l7  = lane & 7;
  const int l15 = lane & 15;
  const int hi  = lane >> 4;          // 0..3
  const int rA  = w * 64 + l15;

  for (int kt = k0; kt < k1; kt += 64) {
#pragma unroll
    for (int i = 0; i < 8; ++i) {
      const int cl  = tid + i * 128;
      const int row = cl >> 3;
      const int j   = (cl & 7) ^ (row & 7);
      gload16(A + (m0 + row) * K + kt + (j << 3), As + cl * 8);
    }
#pragma unroll
    for (int i = 0; i < 4; ++i) {
      const int cl  = tid + i * 128;
      const int row = cl >> 3;
      const int j   = (cl & 7) ^ (row & 7);
      gload16(W + (n0 + row) * K + kt + (j << 3), Bs + cl * 8);
    }
    __syncthreads();
#pragma unroll
    for (int kk = 0; kk < 64; kk += 32) {
      const int ck = ((((kk >> 3) + hi) ^ l7) << 3);   // swizzled chunk offset
      bf16x8 af[4], bfr[4];
#pragma unroll
      for (int m = 0; m < 4; ++m) af[m]  = *(const bf16x8*)(As + (rA + m * 16) * 64 + ck);
#pragma unroll
      for (int n = 0; n < 4; ++n) bfr[n] = *(const bf16x8*)(Bs + (l15 + n * 16) * 64 + ck);
#pragma unroll
      for (int m = 0; m < 4; ++m)
#pragma unroll
        for (int n = 0; n < 4; ++n)
          acc[m][n] = __builtin_amdgcn_mfma_f32_16x16x32_bf16(af[m], bfr[n], acc[m][n], 0, 0, 0);
    }
    __syncthreads();
  }

  // C/D layout: col = lane&15, row = (lane>>4)*4 + reg
  const int lr = hi << 2;
#pragma unroll
  for (int n = 0; n < 4; ++n) {
    const long gcol = n0 + n * 16 + l15;
    float bv = 0.f;
    if (EPI == 0 || EPI == 1) bv = bias[gcol];
    if (EPI == 4 && k0 == 0)  bv = bias[gcol];
#pragma unroll
    for (int m = 0; m < 4; ++m) {
      const long grow0 = m0 + w * 64 + m * 16 + lr;
#pragma unroll
      for (int r = 0; r < 4; ++r) {
        float v = acc[m][n][r] + bv;
        const long idx = (grow0 + r) * N + gcol;
        if (EPI == 0) {
          obf[idx] = (bf16_t)v;
        } else if (EPI == 1) {
          v = 0.5f * v * (1.0f + erff(v * 0.70710678118654752f));
          obf[idx] = (bf16_t)v;
        } else {
          atomicAdd(&of32[idx], v);
        }
      }
    }
  }
}

// ---------------------------------------------------------------------------
// Logits GEMM, 8-phase 256x256 template (T2+T3+T4+T5):
// out[2048,32000] f32 = A[2048,768] @ We[32000,768]^T, both bf16.
// 512 threads = 8 waves (2M x 4N), per-wave 128x64 output, BK=64, 12 K-tiles.
// LDS: 2 bufs x (A 256x64 + B 256x64) = 128 KiB, halves of 128 rows.
// Schedule ledger (per K-tile, 4 phases, 2 barriers each):
//   top:  vmcnt(8) [tile t landed; t+1's 8 loads in flight] ; barrier
//   ph0:  read A(mh0) 8x b128 + B(nh0) 4x       ; MFMA acc[0..3][0,1]
//   ph1:  read B(nh1) 4x                        ; MFMA acc[0..3][2,3]
//   ph2:  read A(mh1) 8x ; stage B(t+2) h0,h1   ; MFMA acc[4..7][2,3]
//         [B LDS last read ph1 -> overwrite safe after ph1 trailing barrier]
//   ph3:  stage A(t+2) h0,h1                    ; MFMA acc[4..7][0,1]
//         [A LDS last read ph2 -> safe]
// vmcnt never drained mid-loop (T4); setprio(1) around MFMA clusters (T5);
// XOR chunk swizzle on stage-source + read (T2, rule #21 both-sides).
// ---------------------------------------------------------------------------
__global__ __launch_bounds__(512, 2) void gemm_logits8(
    const bf16_t* __restrict__ A, const bf16_t* __restrict__ W,
    float* __restrict__ out)
{
  __shared__ bf16_t Abuf[2][2][128 * 64];   // [buf][half][row*64+col]
  __shared__ bf16_t Bbuf[2][2][128 * 64];
  const int tid  = threadIdx.x;
  const int lane = tid & 63;
  const int w    = tid >> 6;      // 0..7
  const int wm   = w >> 2;        // 0..1  (M half)
  const int wn   = w & 3;         // 0..3  (N quarter)
  const int d    = blockIdx.x;    // 0..999
  const int wk   = (d & 7) * 125 + (d >> 3);   // bijective XCD chunking
  const long m0  = (long)(wk & 7) * 256;       // M fastest within chunk
  const long n0  = (long)(wk >> 3) * 256;
  const int K = 768, N = 32000;

  const int l7 = lane & 7, l15 = lane & 15, hi = lane >> 4;

  auto stageA = [&](int t, int h) {
#pragma unroll
    for (int i = 0; i < 2; ++i) {
      const int cl  = tid + i * 512;
      const int row = cl >> 3;
      const int j   = (cl & 7) ^ (row & 7);
      gload16(A + (m0 + h * 128 + row) * K + t * 64 + (j << 3),
              &Abuf[t & 1][h][cl * 8]);
    }
  };
  auto stageB = [&](int t, int h) {
#pragma unroll
    for (int i = 0; i < 2; ++i) {
      const int cl  = tid + i * 512;
      const int row = cl >> 3;
      const int j   = (cl & 7) ^ (row & 7);
      gload16(W + (n0 + h * 128 + row) * K + t * 64 + (j << 3),
              &Bbuf[t & 1][h][cl * 8]);
    }
  };

  f32x4 acc[8][4] = {};
  bf16x8 areg[4][2], breg[4][2];

  // prologue: stage tiles 0 and 1 (16 loads/thread in flight)
  stageA(0, 0); stageA(0, 1); stageB(0, 0); stageB(0, 1);
  stageA(1, 0); stageA(1, 1); stageB(1, 0); stageB(1, 1);

  const int rbB = (wn & 1) * 64;

  for (int t = 0; t < 12; ++t) {
    const int buf = t & 1;
    if (t < 11) asm volatile("s_waitcnt vmcnt(8)" ::: "memory");
    else        asm volatile("s_waitcnt vmcnt(0)" ::: "memory");
    __builtin_amdgcn_s_barrier();
    const bf16_t* Ab = &Abuf[buf][wm][0];
    const bf16_t* Bb = &Bbuf[buf][wn >> 1][0];

    // ---- phase 0: read A mh=0, B nh=0; MFMA acc[0..3][0,1]
#pragma unroll
    for (int kkI = 0; kkI < 2; ++kkI) {
      const int ck = ((((kkI << 2) + hi) ^ l7) << 3);
#pragma unroll
      for (int mq = 0; mq < 4; ++mq)
        areg[mq][kkI] = *(const bf16x8*)(Ab + (mq * 16 + l15) * 64 + ck);
#pragma unroll
      for (int nq = 0; nq < 2; ++nq)
        breg[nq][kkI] = *(const bf16x8*)(Bb + (rbB + nq * 16 + l15) * 64 + ck);
    }
    __builtin_amdgcn_s_barrier();
    __builtin_amdgcn_s_setprio(1);
#pragma unroll
    for (int mq = 0; mq < 4; ++mq)
#pragma unroll
      for (int nq = 0; nq < 2; ++nq)
#pragma unroll
        for (int kkI = 0; kkI < 2; ++kkI)
          acc[mq][nq] = __builtin_amdgcn_mfma_f32_16x16x32_bf16(
              areg[mq][kkI], breg[nq][kkI], acc[mq][nq], 0, 0, 0);
    __builtin_amdgcn_s_setprio(0);
    asm volatile("s_waitcnt lgkmcnt(0)" ::: "memory");
    __builtin_amdgcn_sched_barrier(0);
    __builtin_amdgcn_s_barrier();

    // ---- phase 1: read B nh=1; MFMA acc[0..3][2,3]
#pragma unroll
    for (int kkI = 0; kkI < 2; ++kkI) {
      const int ck = ((((kkI << 2) + hi) ^ l7) << 3);
#pragma unroll
      for (int nq = 0; nq < 2; ++nq)
        breg[2 + nq][kkI] = *(const bf16x8*)(Bb + (rbB + 32 + nq * 16 + l15) * 64 + ck);
    }
    __builtin_amdgcn_s_barrier();
    __builtin_amdgcn_s_setprio(1);
#pragma unroll
    for (int mq = 0; mq < 4; ++mq)
#pragma unroll
      for (int nq = 0; nq < 2; ++nq)
#pragma unroll
        for (int kkI = 0; kkI < 2; ++kkI)
          acc[mq][2 + nq] = __builtin_amdgcn_mfma_f32_16x16x32_bf16(
              areg[mq][kkI], breg[2 + nq][kkI], acc[mq][2 + nq], 0, 0, 0);
    __builtin_amdgcn_s_setprio(0);
    asm volatile("s_waitcnt lgkmcnt(0)" ::: "memory");
    __builtin_amdgcn_sched_barrier(0);
    __builtin_amdgcn_s_barrier();

    // ---- phase 2: read A mh=1; stage B(t+2) both halves; MFMA acc[4..7][2,3]
#pragma unroll
    for (int kkI = 0; kkI < 2; ++kkI) {
      const int ck = ((((kkI << 2) + hi) ^ l7) << 3);
#pragma unroll
      for (int mq = 0; mq < 4; ++mq)
        areg[mq][kkI] = *(const bf16x8*)(Ab + (64 + mq * 16 + l15) * 64 + ck);
    }
    if (t + 2 < 12) { stageB(t + 2, 0); stageB(t + 2, 1); }
    __builtin_amdgcn_s_barrier();
    __builtin_amdgcn_s_setprio(1);
#pragma unroll
    for (int mq = 0; mq < 4; ++mq)
#pragma unroll
      for (int nq = 0; nq < 2; ++nq)
#pragma unroll
        for (int kkI = 0; kkI < 2; ++kkI)
          acc[4 + mq][2 + nq] = __builtin_amdgcn_mfma_f32_16x16x32_bf16(
              areg[mq][kkI], breg[2 + nq][kkI], acc[4 + mq][2 + nq], 0, 0, 0);
    __builtin_amdgcn_s_setprio(0);
    asm volatile("s_waitcnt lgkmcnt(0)" ::: "memory");
    __builtin_amdgcn_sched_barrier(0);
    __builtin_amdgcn_s_barrier();

    // ---- phase 3: stage A(t+2) both halves; MFMA acc[4..7][0,1]
    if (t + 2 < 12) { stageA(t + 2, 0); stageA(t + 2, 1); }
    __builtin_amdgcn_s_barrier();
    __builtin_amdgcn_s_setprio(1);
#pragma unroll
    for (int mq = 0; mq < 4; ++mq)
#pragma unroll
      for (int nq = 0; nq < 2; ++nq)
#pragma unroll
        for (int kkI = 0; kkI < 2; ++kkI)
          acc[4 + mq][nq] = __builtin_amdgcn_mfma_f32_16x16x32_bf16(
              areg[mq][kkI], breg[nq][kkI], acc[4 + mq][nq], 0, 0, 0);
    __builtin_amdgcn_s_setprio(0);
    __builtin_amdgcn_sched_barrier(0);
    // (trailing barrier merged with next tile-top barrier)
  }

  // epilogue: C/D layout col = l15, row = hi*4 + r
#pragma unroll
  for (int mi = 0; mi < 8; ++mi) {
    const long grow0 = m0 + wm * 128 + mi * 16 + hi * 4;
#pragma unroll
    for (int ni = 0; ni < 4; ++ni) {
      const long gcol = n0 + wn * 64 + ni * 16 + l15;
#pragma unroll
      for (int r = 0; r < 4; ++r)
        out[(grow0 + r) * N + gcol] = acc[mi][ni][r];
    }
  }
}

// ---------------------------------------------------------------------------
// V transpose: vT[bh][d][s] <- qkv[b][s][h*192+128+d]; per layer, 3.1 MB.
// ---------------------------------------------------------------------------
__global__ __launch_bounds__(256) void vtrans_kernel(
    const bf16_t* __restrict__ qkv, bf16_t* __restrict__ vT)
{
  __shared__ bf16_t T[128][72];           // +8 pad breaks write-phase conflicts
  const int bh = blockIdx.x;              // 0..23
  const int b = bh / 12, h = bh % 12;
  const int s0 = blockIdx.y * 128;
  const int tid = threadIdx.x;
  const bf16_t* src = qkv + (long)(b * 1024 + s0) * 2304 + h * 192 + 128;
#pragma unroll
  for (int i = 0; i < 4; ++i) {
    const int row = i * 32 + (tid >> 3);
    const int c = (tid & 7) * 8;
    *(bf16x8*)&T[row][c] = *(const bf16x8*)(src + (long)row * 2304 + c);
  }
  __syncthreads();
  const int dd = tid >> 2;                // 0..63
  const int sq = (tid & 3) * 32;          // 0,32,64,96
  bf16_t* dst = vT + ((long)bh * 64 + dd) * 1024 + s0 + sq;
#pragma unroll
  for (int j2 = 0; j2 < 4; ++j2) {
    bf16x8 o;
#pragma unroll
    for (int j = 0; j < 8; ++j) o[j] = T[sq + j2 * 8 + j][dd];
    *(bf16x8*)(dst + j2 * 8) = o;
  }
}

// ---------------------------------------------------------------------------
// Flash attention: one wave per (b, h, 16 q-rows). KV blocks of 64, causal.
// Q,K read from qkv [B][S][2304]; V read from vT [bh][64][1024] (transposed).
// ---------------------------------------------------------------------------
__global__ __launch_bounds__(256) void attn_kernel(
    const bf16_t* __restrict__ qkv, const bf16_t* __restrict__ vT,
    bf16_t* __restrict__ aout)
{
  __shared__ bf16_t Plds[4][16 * 64];
  const int tid  = threadIdx.x;
  const int lane = tid & 63;
  const int w    = tid >> 6;
  const int wid  = blockIdx.x * 4 + w;   // 0..1535
  const int qt   = wid & 63;
  const int bh   = wid >> 6;             // 0..23
  const int b    = bh / 12;
  const int h    = bh % 12;
  const int q0   = qt << 4;

  const bf16_t* base = qkv + (long)b * 1024 * 2304 + h * 192;
  const bf16_t* vtb  = vT + (long)bh * 64 * 1024;
  const int koff  = (lane >> 4) << 3;
  const int l15   = lane & 15;
  const int rbase = (lane >> 4) << 2;

  const bf16x8 qf0 = *(const bf16x8*)(base + (long)(q0 + l15) * 2304 + koff);
  const bf16x8 qf1 = *(const bf16x8*)(base + (long)(q0 + l15) * 2304 + 32 + koff);

  f32x4 acc[4] = {};
  float mrun[4], lrun[4];
#pragma unroll
  for (int r = 0; r < 4; ++r) { mrun[r] = -1e30f; lrun[r] = 0.f; }

  bf16_t* pl = &Plds[w][0];
  const int kbmax = (q0 + 15) >> 6;
  for (int kb = 0; kb <= kbmax; ++kb) {
    const int kv0 = kb << 6;
    const f32x4 z = {0.f, 0.f, 0.f, 0.f};
    f32x4 s[4];
    __builtin_amdgcn_s_setprio(1);
#pragma unroll
    for (int g = 0; g < 4; ++g) {
      const bf16_t* kr = base + 64 + (long)(kv0 + g * 16 + l15) * 2304;
      const bf16x8 ka = *(const bf16x8*)(kr + koff);
      const bf16x8 kb2 = *(const bf16x8*)(kr + 32 + koff);
      s[g] = __builtin_amdgcn_mfma_f32_16x16x32_bf16(qf0, ka, z, 0, 0, 0);
      s[g] = __builtin_amdgcn_mfma_f32_16x16x32_bf16(qf1, kb2, s[g], 0, 0, 0);
    }
    __builtin_amdgcn_s_setprio(0);

#pragma unroll
    for (int r = 0; r < 4; ++r) {
      const int qi = q0 + rbase + r;
      float v[4];
#pragma unroll
      for (int g = 0; g < 4; ++g)
        v[g] = (kv0 + g * 16 + l15 <= qi) ? s[g][r] * 0.125f : -1e9f;
      float mx = fmaxf(fmaxf(v[0], v[1]), fmaxf(v[2], v[3]));
#pragma unroll
      for (int dd = 1; dd < 16; dd <<= 1) mx = fmaxf(mx, __shfl_xor(mx, dd));
      const float mnew = fmaxf(mrun[r], mx);
      const float sc = __expf(mrun[r] - mnew);
      float p[4], sm = 0.f;
#pragma unroll
      for (int g = 0; g < 4; ++g) { p[g] = __expf(v[g] - mnew); sm += p[g]; }
#pragma unroll
      for (int dd = 1; dd < 16; dd <<= 1) sm += __shfl_xor(sm, dd);
      lrun[r] = lrun[r] * sc + sm;
      mrun[r] = mnew;
      acc[0][r] *= sc; acc[1][r] *= sc; acc[2][r] *= sc; acc[3][r] *= sc;
#pragma unroll
      for (int g = 0; g < 4; ++g)
        pl[(rbase + r) * 64 + g * 16 + l15] = (bf16_t)p[g];
    }
    asm volatile("s_waitcnt lgkmcnt(0)" ::: "memory");
    const bf16x8 pf0 = *(const bf16x8*)(pl + l15 * 64 + koff);
    const bf16x8 pf1 = *(const bf16x8*)(pl + l15 * 64 + 32 + koff);
    __builtin_amdgcn_s_setprio(1);
#pragma unroll
    for (int hh = 0; hh < 2; ++hh) {
      const bf16x8 pf = hh ? pf1 : pf0;
      const int sbase = kv0 + hh * 32 + koff;
#pragma unroll
      for (int cb = 0; cb < 4; ++cb) {
        const bf16x8 vf = *(const bf16x8*)(vtb + (long)(cb * 16 + l15) * 1024 + sbase);
        acc[cb] = __builtin_amdgcn_mfma_f32_16x16x32_bf16(pf, vf, acc[cb], 0, 0, 0);
      }
    }
    __builtin_amdgcn_s_setprio(0);
  }

#pragma unroll
  for (int cb = 0; cb < 4; ++cb)
#pragma unroll
    for (int r = 0; r < 4; ++r) {
      const float o = acc[cb][r] / lrun[r];
      aout[(long)(b * 1024 + q0 + rbase + r) * 768 + h * 64 + cb * 16 + l15] = (bf16_t)o;
    }
}

// ---------------------------------------------------------------------------
// LayerNorm over rows of 768, fp32 in -> bf16 out
// ---------------------------------------------------------------------------
__global__ __launch_bounds__(256) void ln_kernel(
    const float* __restrict__ x, const float* __restrict__ g,
    const float* __restrict__ bta, bf16_t* __restrict__ out)
{
  const int row = blockIdx.x;
  const int tid = threadIdx.x;
  const float* xr = x + (long)row * 768;
  const float v0 = xr[tid], v1 = xr[tid + 256], v2 = xr[tid + 512];
  float s  = v0 + v1 + v2;
  float ss = v0 * v0 + v1 * v1 + v2 * v2;
#pragma unroll
  for (int d = 1; d < 64; d <<= 1) { s += __shfl_xor(s, d); ss += __shfl_xor(ss, d); }
  __shared__ float sh[8];
  const int lane = tid & 63, wv = tid >> 6;
  if (lane == 0) { sh[wv] = s; sh[4 + wv] = ss; }
  __syncthreads();
  s  = sh[0] + sh[1] + sh[2] + sh[3];
  ss = sh[4] + sh[5] + sh[6] + sh[7];
  const float mean = s * (1.0f / 768.0f);
  const float var  = ss * (1.0f / 768.0f) - mean * mean;
  const float inv  = rsqrtf(var + 1e-5f);
  bf16_t* orow = out + (long)row * 768;
  orow[tid]       = (bf16_t)(g[tid]       * ((v0 - mean) * inv) + bta[tid]);
  orow[tid + 256] = (bf16_t)(g[tid + 256] * ((v1 - mean) * inv) + bta[tid + 256]);
  orow[tid + 512] = (bf16_t)(g[tid + 512] * ((v2 - mean) * inv) + bta[tid + 512]);
}

// ---------------------------------------------------------------------------
// Embedding: x[b,s,:] = W_emb[id]*sqrt(768) + pos[s]
// ---------------------------------------------------------------------------
__global__ __launch_bounds__(256) void embed_kernel(
    const int* __restrict__ ids, const float* __restrict__ We,
    const float* __restrict__ pos, float* __restrict__ x)
{
  const int row = blockIdx.x;
  const int tid = threadIdx.x;
  const int s = row & 1023;
  const long id = ids[row];
  const float* wr = We + id * 768;
  const float* pr = pos + (long)s * 768;
  float* xr = x + (long)row * 768;
#pragma unroll
  for (int k = 0; k < 3; ++k) {
    const int c = tid + k * 256;
    xr[c] = wr[c] * 27.712812921102035f + pr[c];
  }
}

// fp32 -> bf16 weight conversion
__global__ __launch_bounds__(256) void cvt_kernel(
    const float* __restrict__ in, bf16_t* __restrict__ out, long n)
{
  const long i = ((long)blockIdx.x * 256 + threadIdx.x) * 8;
  if (i >= n) return;
  bf16x8 o;
#pragma unroll
  for (int j = 0; j < 8; ++j) o[j] = (bf16_t)in[i + j];
  *(bf16x8*)(out + i) = o;
}

// ---------------------------------------------------------------------------
extern "C" void kernel_launch(void* const* d_in, const int* in_sizes, int n_in,
                              void* d_out, int out_size, void* d_ws, size_t ws_size,
                              hipStream_t stream)
{
  const float* W_emb = (const float*)d_in[0];
  const float* pos   = (const float*)d_in[1];
  const float* n1g   = (const float*)d_in[2];
  const float* n1b   = (const float*)d_in[3];
  const float* qkvw  = (const float*)d_in[4];
  const float* qkvb  = (const float*)d_in[5];
  const float* projw = (const float*)d_in[6];
  const float* projb = (const float*)d_in[7];
  const float* n2g   = (const float*)d_in[8];
  const float* n2b   = (const float*)d_in[9];
  const float* f1w   = (const float*)d_in[10];
  const float* f1b   = (const float*)d_in[11];
  const float* f2w   = (const float*)d_in[12];
  const float* f2b   = (const float*)d_in[13];
  const float* fing  = (const float*)d_in[14];
  const float* finb  = (const float*)d_in[15];
  const int*   ids   = (const int*)d_in[16];
  float* out = (float*)d_out;

  char* ws = (char*)d_ws;
  float*  x     = (float*)(ws);                 // 2048*768 f32   = 6291456 B
  bf16_t* h     = (bf16_t*)(ws + 6291456);      // 2048*768 bf16  = 3145728 B
  bf16_t* qkv   = (bf16_t*)(ws + 9437184);      // 2048*2304 bf16 = 9437184 B
  bf16_t* attn  = (bf16_t*)(ws + 18874368);     // 2048*768 bf16
  bf16_t* ffn1o = (bf16_t*)(ws + 22020096);     // 2048*3072 bf16 = 12582912 B
  bf16_t* Wq    = (bf16_t*)(ws + 34603008);     // 4*2304*768
  bf16_t* Wp    = (bf16_t*)(ws + 48758784);     // 4*768*768
  bf16_t* W1    = (bf16_t*)(ws + 53477376);     // 4*3072*768
  bf16_t* W2    = (bf16_t*)(ws + 72351744);     // 4*768*3072
  bf16_t* We    = (bf16_t*)(ws + 91226112);     // 32000*768
  bf16_t* vT    = (bf16_t*)(ws + 140378112);    // 24*64*1024 bf16 = 3145728 B

  cvt_kernel<<<dim3(3456),  256, 0, stream>>>(qkvw,  Wq, 4L * 2304 * 768);
  cvt_kernel<<<dim3(1152),  256, 0, stream>>>(projw, Wp, 4L * 768 * 768);
  cvt_kernel<<<dim3(4608),  256, 0, stream>>>(f1w,   W1, 4L * 3072 * 768);
  cvt_kernel<<<dim3(4608),  256, 0, stream>>>(f2w,   W2, 4L * 768 * 3072);
  cvt_kernel<<<dim3(12000), 256, 0, stream>>>(W_emb, We, 32000L * 768);

  embed_kernel<<<2048, 256, 0, stream>>>(ids, W_emb, pos, x);

  for (int i = 0; i < 4; ++i) {
    ln_kernel<<<2048, 256, 0, stream>>>(x, n1g + i * 768, n1b + i * 768, h);
    gemm_bt<0><<<dim3(36, 16), 128, 0, stream>>>(
        h, Wq + (long)i * 2304 * 768, qkvb + i * 2304, qkv, nullptr, 2048, 2304, 768, 768);
    vtrans_kernel<<<dim3(24, 8), 256, 0, stream>>>(qkv, vT);
    attn_kernel<<<384, 256, 0, stream>>>(qkv, vT, attn);
    gemm_bt<4><<<dim3(12, 16, 2), 128, 0, stream>>>(
        attn, Wp + (long)i * 768 * 768, projb + i * 768, nullptr, x, 2048, 768, 768, 384);
    ln_kernel<<<2048, 256, 0, stream>>>(x, n2g + i * 768, n2b + i * 768, h);
    gemm_bt<1><<<dim3(48, 16), 128, 0, stream>>>(
        h, W1 + (long)i * 3072 * 768, f1b + i * 3072, ffn1o, nullptr, 2048, 3072, 768, 768);
    gemm_bt<4><<<dim3(12, 16, 4), 128, 0, stream>>>(
        ffn1o, W2 + (long)i * 768 * 3072, f2b + i * 768, nullptr, x, 2048, 768, 3072, 768);
  }
  ln_kernel<<<2048, 256, 0, stream>>>(x, fing, finb, h);
  gemm_logits8<<<dim3(1000), 512, 0, stream>>>(h, We, out);
}

// Round 7
// 839.142 us; speedup vs baseline: 1.0802x; 1.0802x over previous
//
#include <hip/hip_runtime.h>
#include <hip/hip_bf16.h>
#include <math.h>

typedef __bf16 bf16_t;
typedef __bf16 bf16x8 __attribute__((ext_vector_type(8)));
typedef float f32x4 __attribute__((ext_vector_type(4)));

// async 16B global->LDS (LDS dest must be wave-uniform base + lane*16)
__device__ __forceinline__ void gload16(const bf16_t* g, bf16_t* l) {
  __builtin_amdgcn_global_load_lds(
      (const __attribute__((address_space(1))) unsigned int*)g,
      (__attribute__((address_space(3))) unsigned int*)l, 16, 0, 0);
}

// LDS tiles are [rows][64] bf16 (128 B row stride), contents XOR-swizzled:
// LDS[row][chunk j] holds G[row][chunk j ^ (row&7)]  (chunk = 8 bf16 = 16 B).

// ---------------------------------------------------------------------------
// Layer GEMM: out[M,N] = A[M,K] @ W[N,K]^T (+bias, +epilogue)
// EPI 0: bf16 out = acc + bias            (generic)
// EPI 5: EPI0 + side-write V third into vT[bh][d][s]   (QKV, fused vtrans)
// EPI 1: bf16 out = gelu(acc + bias)      (FFN1)
// EPI 4: f32 atomicAdd(out, acc [+bias])  (proj / FFN2 split-K residual)
// Tile 128(M)x64(N), BK=64, 128 threads = 2 waves, each wave 64x64.
// ---------------------------------------------------------------------------
template<int EPI>
__global__ __launch_bounds__(128, 3) void gemm_bt(
    const bf16_t* __restrict__ A, const bf16_t* __restrict__ W,
    const float* __restrict__ bias,
    bf16_t* __restrict__ obf, float* __restrict__ of32, bf16_t* __restrict__ vt,
    int M, int N, int K, int kLen)
{
  __shared__ bf16_t As[128 * 64];
  __shared__ bf16_t Bs[64 * 64];
  const int tid  = threadIdx.x;
  const int lane = tid & 63;
  const int w    = tid >> 6;          // 0..1, wave's 64-row band
  const long m0 = (long)blockIdx.y * 128;
  const long n0 = (long)blockIdx.x * 64;
  const int k0 = blockIdx.z * kLen;
  const int k1 = k0 + kLen;

  f32x4 acc[4][4] = {};

  const int l7  = lane & 7;
  const int l15 = lane & 15;
  const int hi  = lane >> 4;          // 0..3
  const int rA  = w * 64 + l15;

  for (int kt = k0; kt < k1; kt += 64) {
#pragma unroll
    for (int i = 0; i < 8; ++i) {
      const int cl  = tid + i * 128;
      const int row = cl >> 3;
      const int j   = (cl & 7) ^ (row & 7);
      gload16(A + (m0 + row) * K + kt + (j << 3), As + cl * 8);
    }
#pragma unroll
    for (int i = 0; i < 4; ++i) {
      const int cl  = tid + i * 128;
      const int row = cl >> 3;
      const int j   = (cl & 7) ^ (row & 7);
      gload16(W + (n0 + row) * K + kt + (j << 3), Bs + cl * 8);
    }
    __syncthreads();
#pragma unroll
    for (int kk = 0; kk < 64; kk += 32) {
      const int ck = ((((kk >> 3) + hi) ^ l7) << 3);   // swizzled chunk offset
      bf16x8 af[4], bfr[4];
#pragma unroll
      for (int m = 0; m < 4; ++m) af[m]  = *(const bf16x8*)(As + (rA + m * 16) * 64 + ck);
#pragma unroll
      for (int n = 0; n < 4; ++n) bfr[n] = *(const bf16x8*)(Bs + (l15 + n * 16) * 64 + ck);
#pragma unroll
      for (int m = 0; m < 4; ++m)
#pragma unroll
        for (int n = 0; n < 4; ++n)
          acc[m][n] = __builtin_amdgcn_mfma_f32_16x16x32_bf16(af[m], bfr[n], acc[m][n], 0, 0, 0);
    }
    __syncthreads();
  }

  // C/D layout: col = lane&15, row = (lane>>4)*4 + reg
  const int lr = hi << 2;
#pragma unroll
  for (int n = 0; n < 4; ++n) {
    const long gcol = n0 + n * 16 + l15;
    float bv = 0.f;
    if (EPI == 0 || EPI == 1 || EPI == 5) bv = bias[gcol];
    if (EPI == 4 && k0 == 0)  bv = bias[gcol];
    const int hq = (int)gcol / 192;          // head (EPI5)
    const int c  = (int)gcol - hq * 192;     // col within head
#pragma unroll
    for (int m = 0; m < 4; ++m) {
      const long grow0 = m0 + w * 64 + m * 16 + lr;
#pragma unroll
      for (int r = 0; r < 4; ++r) {
        float v = acc[m][n][r] + bv;
        const long idx = (grow0 + r) * N + gcol;
        if (EPI == 0 || EPI == 5) {
          obf[idx] = (bf16_t)v;
          if (EPI == 5 && c >= 128) {
            const int row = (int)(grow0 + r);
            const int bb = row >> 10, ss = row & 1023;
            vt[(((long)bb * 12 + hq) * 64 + (c - 128)) * 1024 + ss] = (bf16_t)v;
          }
        } else if (EPI == 1) {
          v = 0.5f * v * (1.0f + erff(v * 0.70710678118654752f));
          obf[idx] = (bf16_t)v;
        } else {
          atomicAdd(&of32[idx], v);
        }
      }
    }
  }
}

// ---------------------------------------------------------------------------
// Logits GEMM: out[2048,32000] f32 = A[2048,768] @ We[32000,768]^T, both bf16.
// 256-thread 128x128 2-phase structure, BK=64, swizzled LDS, XCD-chunked
// M-fastest grid. fp32 output via NON-TEMPORAL stores (don't evict W in L2).
// ---------------------------------------------------------------------------
__global__ __launch_bounds__(256, 2) void gemm_logits(
    const bf16_t* __restrict__ A, const bf16_t* __restrict__ W,
    float* __restrict__ out)
{
  __shared__ bf16_t As[128 * 64];
  __shared__ bf16_t Bs[128 * 64];
  const int tid  = threadIdx.x;
  const int lane = tid & 63;
  const int w    = tid >> 6;
  const int wr   = w >> 1;
  const int wc   = w & 1;
  const int d    = blockIdx.x;            // 0..3999
  const int wk   = (d & 7) * 500 + (d >> 3);
  const long m0  = (long)(wk & 15) * 128; // M fastest within XCD chunk
  const long n0  = (long)(wk >> 4) * 128;
  const int K = 768, N = 32000;

  f32x4 acc[4][4] = {};
  const int l7  = lane & 7;
  const int l15 = lane & 15;
  const int hi  = lane >> 4;
  const int rA  = wr * 64 + l15;
  const int rB  = wc * 64 + l15;

  for (int kt = 0; kt < K; kt += 64) {
#pragma unroll
    for (int i = 0; i < 4; ++i) {
      const int cl  = tid + i * 256;
      const int row = cl >> 3;
      const int j   = (cl & 7) ^ (row & 7);
      gload16(A + (m0 + row) * K + kt + (j << 3), As + cl * 8);
    }
#pragma unroll
    for (int i = 0; i < 4; ++i) {
      const int cl  = tid + i * 256;
      const int row = cl >> 3;
      const int j   = (cl & 7) ^ (row & 7);
      gload16(W + (n0 + row) * K + kt + (j << 3), Bs + cl * 8);
    }
    __syncthreads();
#pragma unroll
    for (int kk = 0; kk < 64; kk += 32) {
      const int ck = ((((kk >> 3) + hi) ^ l7) << 3);
      bf16x8 af[4], bfr[4];
#pragma unroll
      for (int m = 0; m < 4; ++m) af[m]  = *(const bf16x8*)(As + (rA + m * 16) * 64 + ck);
#pragma unroll
      for (int n = 0; n < 4; ++n) bfr[n] = *(const bf16x8*)(Bs + (rB + n * 16) * 64 + ck);
#pragma unroll
      for (int m = 0; m < 4; ++m)
#pragma unroll
        for (int n = 0; n < 4; ++n)
          acc[m][n] = __builtin_amdgcn_mfma_f32_16x16x32_bf16(af[m], bfr[n], acc[m][n], 0, 0, 0);
    }
    __syncthreads();
  }

  const int lr = hi << 2;
#pragma unroll
  for (int n = 0; n < 4; ++n) {
    const long gcol = n0 + wc * 64 + n * 16 + l15;
#pragma unroll
    for (int m = 0; m < 4; ++m) {
      const long grow0 = m0 + wr * 64 + m * 16 + lr;
#pragma unroll
      for (int r = 0; r < 4; ++r)
        __builtin_nontemporal_store(acc[m][n][r], &out[(grow0 + r) * N + gcol]);
    }
  }
}

// ---------------------------------------------------------------------------
// Flash attention: one wave per (b, h, 16 q-rows). KV blocks of 64, causal.
// Q,K read from qkv [B][S][2304]; V read from vT [bh][64][1024] (transposed).
// ---------------------------------------------------------------------------
__global__ __launch_bounds__(256) void attn_kernel(
    const bf16_t* __restrict__ qkv, const bf16_t* __restrict__ vT,
    bf16_t* __restrict__ aout)
{
  __shared__ bf16_t Plds[4][16 * 64];
  const int tid  = threadIdx.x;
  const int lane = tid & 63;
  const int w    = tid >> 6;
  const int wid  = blockIdx.x * 4 + w;   // 0..1535
  const int qt   = wid & 63;
  const int bh   = wid >> 6;             // 0..23
  const int b    = bh / 12;
  const int h    = bh % 12;
  const int q0   = qt << 4;

  const bf16_t* base = qkv + (long)b * 1024 * 2304 + h * 192;
  const bf16_t* vtb  = vT + (long)bh * 64 * 1024;
  const int koff  = (lane >> 4) << 3;
  const int l15   = lane & 15;
  const int rbase = (lane >> 4) << 2;

  const bf16x8 qf0 = *(const bf16x8*)(base + (long)(q0 + l15) * 2304 + koff);
  const bf16x8 qf1 = *(const bf16x8*)(base + (long)(q0 + l15) * 2304 + 32 + koff);

  f32x4 acc[4] = {};
  float mrun[4], lrun[4];
#pragma unroll
  for (int r = 0; r < 4; ++r) { mrun[r] = -1e30f; lrun[r] = 0.f; }

  bf16_t* pl = &Plds[w][0];
  const int kbmax = (q0 + 15) >> 6;
  for (int kb = 0; kb <= kbmax; ++kb) {
    const int kv0 = kb << 6;
    const f32x4 z = {0.f, 0.f, 0.f, 0.f};
    f32x4 s[4];
    __builtin_amdgcn_s_setprio(1);
#pragma unroll
    for (int g = 0; g < 4; ++g) {
      const bf16_t* kr = base + 64 + (long)(kv0 + g * 16 + l15) * 2304;
      const bf16x8 ka = *(const bf16x8*)(kr + koff);
      const bf16x8 kb2 = *(const bf16x8*)(kr + 32 + koff);
      s[g] = __builtin_amdgcn_mfma_f32_16x16x32_bf16(qf0, ka, z, 0, 0, 0);
      s[g] = __builtin_amdgcn_mfma_f32_16x16x32_bf16(qf1, kb2, s[g], 0, 0, 0);
    }
    __builtin_amdgcn_s_setprio(0);

#pragma unroll
    for (int r = 0; r < 4; ++r) {
      const int qi = q0 + rbase + r;
      float v[4];
#pragma unroll
      for (int g = 0; g < 4; ++g)
        v[g] = (kv0 + g * 16 + l15 <= qi) ? s[g][r] * 0.125f : -1e9f;
      float mx = fmaxf(fmaxf(v[0], v[1]), fmaxf(v[2], v[3]));
#pragma unroll
      for (int dd = 1; dd < 16; dd <<= 1) mx = fmaxf(mx, __shfl_xor(mx, dd));
      const float mnew = fmaxf(mrun[r], mx);
      const float sc = __expf(mrun[r] - mnew);
      float p[4], sm = 0.f;
#pragma unroll
      for (int g = 0; g < 4; ++g) { p[g] = __expf(v[g] - mnew); sm += p[g]; }
#pragma unroll
      for (int dd = 1; dd < 16; dd <<= 1) sm += __shfl_xor(sm, dd);
      lrun[r] = lrun[r] * sc + sm;
      mrun[r] = mnew;
      acc[0][r] *= sc; acc[1][r] *= sc; acc[2][r] *= sc; acc[3][r] *= sc;
#pragma unroll
      for (int g = 0; g < 4; ++g)
        pl[(rbase + r) * 64 + g * 16 + l15] = (bf16_t)p[g];
    }
    asm volatile("s_waitcnt lgkmcnt(0)" ::: "memory");
    const bf16x8 pf0 = *(const bf16x8*)(pl + l15 * 64 + koff);
    const bf16x8 pf1 = *(const bf16x8*)(pl + l15 * 64 + 32 + koff);
    __builtin_amdgcn_s_setprio(1);
#pragma unroll
    for (int hh = 0; hh < 2; ++hh) {
      const bf16x8 pf = hh ? pf1 : pf0;
      const int sbase = kv0 + hh * 32 + koff;
#pragma unroll
      for (int cb = 0; cb < 4; ++cb) {
        const bf16x8 vf = *(const bf16x8*)(vtb + (long)(cb * 16 + l15) * 1024 + sbase);
        acc[cb] = __builtin_amdgcn_mfma_f32_16x16x32_bf16(pf, vf, acc[cb], 0, 0, 0);
      }
    }
    __builtin_amdgcn_s_setprio(0);
  }

#pragma unroll
  for (int cb = 0; cb < 4; ++cb)
#pragma unroll
    for (int r = 0; r < 4; ++r) {
      const float o = acc[cb][r] / lrun[r];
      aout[(long)(b * 1024 + q0 + rbase + r) * 768 + h * 64 + cb * 16 + l15] = (bf16_t)o;
    }
}

// ---------------------------------------------------------------------------
// LayerNorm over rows of 768, fp32 in -> bf16 out
// ---------------------------------------------------------------------------
__global__ __launch_bounds__(256) void ln_kernel(
    const float* __restrict__ x, const float* __restrict__ g,
    const float* __restrict__ bta, bf16_t* __restrict__ out)
{
  const int row = blockIdx.x;
  const int tid = threadIdx.x;
  const float* xr = x + (long)row * 768;
  const float v0 = xr[tid], v1 = xr[tid + 256], v2 = xr[tid + 512];
  float s  = v0 + v1 + v2;
  float ss = v0 * v0 + v1 * v1 + v2 * v2;
#pragma unroll
  for (int d = 1; d < 64; d <<= 1) { s += __shfl_xor(s, d); ss += __shfl_xor(ss, d); }
  __shared__ float sh[8];
  const int lane = tid & 63, wv = tid >> 6;
  if (lane == 0) { sh[wv] = s; sh[4 + wv] = ss; }
  __syncthreads();
  s  = sh[0] + sh[1] + sh[2] + sh[3];
  ss = sh[4] + sh[5] + sh[6] + sh[7];
  const float mean = s * (1.0f / 768.0f);
  const float var  = ss * (1.0f / 768.0f) - mean * mean;
  const float inv  = rsqrtf(var + 1e-5f);
  bf16_t* orow = out + (long)row * 768;
  orow[tid]       = (bf16_t)(g[tid]       * ((v0 - mean) * inv) + bta[tid]);
  orow[tid + 256] = (bf16_t)(g[tid + 256] * ((v1 - mean) * inv) + bta[tid + 256]);
  orow[tid + 512] = (bf16_t)(g[tid + 512] * ((v2 - mean) * inv) + bta[tid + 512]);
}

// ---------------------------------------------------------------------------
// Embedding: x[b,s,:] = W_emb[id]*sqrt(768) + pos[s]
// ---------------------------------------------------------------------------
__global__ __launch_bounds__(256) void embed_kernel(
    const int* __restrict__ ids, const float* __restrict__ We,
    const float* __restrict__ pos, float* __restrict__ x)
{
  const int row = blockIdx.x;
  const int tid = threadIdx.x;
  const int s = row & 1023;
  const long id = ids[row];
  const float* wr = We + id * 768;
  const float* pr = pos + (long)s * 768;
  float* xr = x + (long)row * 768;
#pragma unroll
  for (int k = 0; k < 3; ++k) {
    const int c = tid + k * 256;
    xr[c] = wr[c] * 27.712812921102035f + pr[c];
  }
}

// ---------------------------------------------------------------------------
// Fused fp32 -> bf16 conversion of all 5 weight tensors (contiguous outputs).
// Segment boundaries in 2048-element blocks: 3456 / 1152 / 4608 / 4608 / 12000.
// ---------------------------------------------------------------------------
__global__ __launch_bounds__(256) void cvt_all_kernel(
    const float* __restrict__ s0, const float* __restrict__ s1,
    const float* __restrict__ s2, const float* __restrict__ s3,
    const float* __restrict__ s4, bf16_t* __restrict__ out)
{
  const int b = blockIdx.x;
  const float* src; long rel, obase;
  if      (b < 3456)  { src = s0; rel = (long)b * 2048;          obase = 0;        }
  else if (b < 4608)  { src = s1; rel = (long)(b - 3456) * 2048; obase = 7077888;  }
  else if (b < 9216)  { src = s2; rel = (long)(b - 4608) * 2048; obase = 9437184;  }
  else if (b < 13824) { src = s3; rel = (long)(b - 9216) * 2048; obase = 18874368; }
  else                { src = s4; rel = (long)(b - 13824) * 2048; obase = 28311552; }
  const long i = rel + (long)threadIdx.x * 8;
  const f32x4 a = *(const f32x4*)(src + i);
  const f32x4 c = *(const f32x4*)(src + i + 4);
  bf16x8 o;
#pragma unroll
  for (int j = 0; j < 4; ++j) { o[j] = (bf16_t)a[j]; o[4 + j] = (bf16_t)c[j]; }
  *(bf16x8*)(out + obase + i) = o;
}

// ---------------------------------------------------------------------------
extern "C" void kernel_launch(void* const* d_in, const int* in_sizes, int n_in,
                              void* d_out, int out_size, void* d_ws, size_t ws_size,
                              hipStream_t stream)
{
  const float* W_emb = (const float*)d_in[0];
  const float* pos   = (const float*)d_in[1];
  const float* n1g   = (const float*)d_in[2];
  const float* n1b   = (const float*)d_in[3];
  const float* qkvw  = (const float*)d_in[4];
  const float* qkvb  = (const float*)d_in[5];
  const float* projw = (const float*)d_in[6];
  const float* projb = (const float*)d_in[7];
  const float* n2g   = (const float*)d_in[8];
  const float* n2b   = (const float*)d_in[9];
  const float* f1w   = (const float*)d_in[10];
  const float* f1b   = (const float*)d_in[11];
  const float* f2w   = (const float*)d_in[12];
  const float* f2b   = (const float*)d_in[13];
  const float* fing  = (const float*)d_in[14];
  const float* finb  = (const float*)d_in[15];
  const int*   ids   = (const int*)d_in[16];
  float* out = (float*)d_out;

  char* ws = (char*)d_ws;
  float*  x     = (float*)(ws);                 // 2048*768 f32   = 6291456 B
  bf16_t* h     = (bf16_t*)(ws + 6291456);      // 2048*768 bf16  = 3145728 B
  bf16_t* qkv   = (bf16_t*)(ws + 9437184);      // 2048*2304 bf16 = 9437184 B
  bf16_t* attn  = (bf16_t*)(ws + 18874368);     // 2048*768 bf16
  bf16_t* ffn1o = (bf16_t*)(ws + 22020096);     // 2048*3072 bf16 = 12582912 B
  bf16_t* Wq    = (bf16_t*)(ws + 34603008);     // 4*2304*768   } contiguous
  bf16_t* Wp    = (bf16_t*)(ws + 48758784);     // 4*768*768    }
  bf16_t* W1    = (bf16_t*)(ws + 53477376);     // 4*3072*768   }
  bf16_t* W2    = (bf16_t*)(ws + 72351744);     // 4*768*3072   }
  bf16_t* We    = (bf16_t*)(ws + 91226112);     // 32000*768    }
  bf16_t* vT    = (bf16_t*)(ws + 140378112);    // 24*64*1024 bf16 = 3145728 B

  cvt_all_kernel<<<dim3(25824), 256, 0, stream>>>(qkvw, projw, f1w, f2w, W_emb, Wq);

  embed_kernel<<<2048, 256, 0, stream>>>(ids, W_emb, pos, x);

  for (int i = 0; i < 4; ++i) {
    ln_kernel<<<2048, 256, 0, stream>>>(x, n1g + i * 768, n1b + i * 768, h);
    gemm_bt<5><<<dim3(36, 16), 128, 0, stream>>>(
        h, Wq + (long)i * 2304 * 768, qkvb + i * 2304, qkv, nullptr, vT,
        2048, 2304, 768, 768);
    attn_kernel<<<384, 256, 0, stream>>>(qkv, vT, attn);
    gemm_bt<4><<<dim3(12, 16, 2), 128, 0, stream>>>(
        attn, Wp + (long)i * 768 * 768, projb + i * 768, nullptr, x, nullptr,
        2048, 768, 768, 384);
    ln_kernel<<<2048, 256, 0, stream>>>(x, n2g + i * 768, n2b + i * 768, h);
    gemm_bt<1><<<dim3(48, 16), 128, 0, stream>>>(
        h, W1 + (long)i * 3072 * 768, f1b + i * 3072, ffn1o, nullptr, nullptr,
        2048, 3072, 768, 768);
    gemm_bt<4><<<dim3(12, 16, 4), 128, 0, stream>>>(
        ffn1o, W2 + (long)i * 768 * 3072, f2b + i * 768, nullptr, x, nullptr,
        2048, 768, 3072, 768);
  }
  ln_kernel<<<2048, 256, 0, stream>>>(x, fing, finb, h);
  gemm_logits<<<dim3(4000), 256, 0, stream>>>(h, We, out);
}